// Round 1
// baseline (959.166 us; speedup 1.0000x reference)
//
#include <hip/hip_runtime.h>
#include <math.h>

// Fused HENN MLP: gather -> segment_sum -> Linear(256,256)+ReLU -> Linear(256,1) -> sigmoid
// One block = 64 consecutive hyperedge segments. 256 threads (4 waves).
// Phase 1: binary-search segment bounds in sorted target_ids; coalesced float4
//          gather of x rows, accumulate per-segment sums into LDS Z[64][256].
// Phase 2: thread h computes column h of Y = relu(Z @ W1^T + b1) for all 64
//          segments; Z read from LDS as broadcast ds_read_b128 (conflict-free),
//          W1 row read per-thread (L2-resident, amortized 64x over segments).
// Phase 3: y2 = relu(Y) @ W2^T + b2 via 64-lane shfl butterfly + LDS cross-wave
//          reduce, sigmoid, store.

__device__ __forceinline__ int lbound(const int* __restrict__ t, int P, int key) {
  int lo = 0, hi = P;
  while (lo < hi) {
    int mid = (lo + hi) >> 1;
    if (t[mid] < key) lo = mid + 1; else hi = mid;
  }
  return lo;
}

__global__ __launch_bounds__(256, 2) void henn_fused(
    const float* __restrict__ x,
    const int* __restrict__ tnodes,
    const int* __restrict__ tids,
    const float* __restrict__ W1,
    const float* __restrict__ b1,
    const float* __restrict__ W2,
    const float* __restrict__ b2,
    float* __restrict__ out,
    int P, int E)
{
  __shared__ float Zl[64][256];   // 64 KB: segment-sum tile, then reused for reduction
  const int tid  = threadIdx.x;
  const int wid  = tid >> 6;      // wave id 0..3
  const int lane = tid & 63;
  const int e0   = blockIdx.x * 64;

  // ---- Phase 1: segment-sum gather into LDS ----
  {
    const int sBeg = wid * 16;
    int lo = lbound(tids, P, e0 + sBeg);            // wave-uniform
    for (int s = sBeg; s < sBeg + 16; ++s) {
      const int e = e0 + s;
      const int hi = lbound(tids, P, e + 1);        // wave-uniform
      float ax = 0.f, ay = 0.f, az = 0.f, aw = 0.f;
      for (int p = lo; p < hi; ++p) {
        const int node = tnodes[p];                 // wave-uniform load
        const float4 v = ((const float4*)(x + (size_t)node * 256))[lane]; // coalesced 1KB/wave
        ax += v.x; ay += v.y; az += v.z; aw += v.w;
      }
      float4 r; r.x = ax; r.y = ay; r.z = az; r.w = aw;
      *(float4*)(&Zl[s][lane * 4]) = r;
      lo = hi;
    }
  }
  __syncthreads();

  // ---- Phase 2: Y[s][h] = b1[h] + sum_d Z[s][d] * W1[h][d], h = tid ----
  const int h = tid;
  const float b1h = b1[h];
  float acc[64];
#pragma unroll
  for (int s = 0; s < 64; ++s) acc[s] = b1h;

  const float4* __restrict__ w1row = (const float4*)(W1 + (size_t)h * 256);
#pragma unroll 2
  for (int d4 = 0; d4 < 64; ++d4) {
    const float4 w = w1row[d4];
#pragma unroll
    for (int s = 0; s < 64; ++s) {
      const float4 z = *(const float4*)(&Zl[s][d4 * 4]);  // broadcast, conflict-free
      acc[s] = fmaf(w.x, z.x, acc[s]);
      acc[s] = fmaf(w.y, z.y, acc[s]);
      acc[s] = fmaf(w.z, z.z, acc[s]);
      acc[s] = fmaf(w.w, z.w, acc[s]);
    }
  }
  __syncthreads();   // all Zl reads done; safe to reuse Zl as reduction scratch

  // ---- Phase 3: second layer + sigmoid ----
  const float w2h = W2[h];
  float* red = (float*)Zl;          // [4][64] per-wave partials
  for (int s = 0; s < 64; ++s) {
    const float r = acc[s] > 0.f ? acc[s] : 0.f;
    float v = w2h * r;
    v += __shfl_xor(v, 32);
    v += __shfl_xor(v, 16);
    v += __shfl_xor(v, 8);
    v += __shfl_xor(v, 4);
    v += __shfl_xor(v, 2);
    v += __shfl_xor(v, 1);
    if (lane == 0) red[wid * 64 + s] = v;
  }
  __syncthreads();

  if (tid < 64) {
    const int e = e0 + tid;
    if (e < E) {
      const float v = red[tid] + red[64 + tid] + red[128 + tid] + red[192 + tid] + b2[0];
      out[e] = 1.f / (1.f + expf(-v));
    }
  }
}

extern "C" void kernel_launch(void* const* d_in, const int* in_sizes, int n_in,
                              void* d_out, int out_size, void* d_ws, size_t ws_size,
                              hipStream_t stream) {
  const float* x      = (const float*)d_in[0];
  const int*   tnodes = (const int*)d_in[1];
  const int*   tids   = (const int*)d_in[2];
  const float* W1     = (const float*)d_in[3];
  const float* b1     = (const float*)d_in[4];
  const float* W2     = (const float*)d_in[5];
  const float* b2     = (const float*)d_in[6];
  (void)d_ws; (void)ws_size; (void)n_in;

  const int P = in_sizes[1];     // 800000 incidence pairs
  const int E = out_size;        // 100000 hyperedges

  const int blocks = (E + 63) / 64;
  henn_fused<<<blocks, 256, 0, stream>>>(x, tnodes, tids, W1, b1, W2, b2,
                                         (float*)d_out, P, E);
}

// Round 2
// 178.815 us; speedup vs baseline: 5.3640x; 5.3640x over previous
//
#include <hip/hip_runtime.h>
#include <math.h>

// Fused HENN MLP: gather -> segment_sum -> Linear(256,256)+ReLU -> Linear(256,1) -> sigmoid
//
// Pipeline (3 kernels, all on `stream`):
//  1. build_segptr: seg_ptr[e] = lower_bound(tids, e) for e in [0,E]  (d_ws)
//  2. conv_w1:      W1 f32 -> bf16 row-major [256][256]               (d_ws)
//  3. henn_main:    1 block = 64 segments, 256 threads (4 waves):
//       Phase 1: gather+segment-sum x rows (f32 acc), store bf16 Z tile in LDS
//                (XOR-swizzled to kill stride-512B bank conflicts)
//       Phase 2: Y = relu(Z @ W1^T + b1) via mfma_f32_16x16x32_bf16;
//                wave w owns h-slice [64w, 64w+64): 4x4 frag tile, K=256
//       Phase 3: y2 = Y @ W2^T + b2 -> sigmoid; 16-lane shfl reduce + LDS
//                cross-wave reduce.

typedef __attribute__((ext_vector_type(8))) short bf16x8;
typedef __attribute__((ext_vector_type(4))) float f32x4;

#define W1B_OFF (512 * 1024)   // d_ws byte offset of bf16 W1 (seg_ptr needs 400 KB)

__device__ __forceinline__ ushort f2bf(float f) {   // RNE f32->bf16
  unsigned u = __float_as_uint(f);
  unsigned r = (u + 0x7FFF + ((u >> 16) & 1)) >> 16;
  return (ushort)r;
}

__global__ void build_segptr(const int* __restrict__ tids, int* __restrict__ ptr,
                             int P, int E) {
  int p = blockIdx.x * 256 + threadIdx.x;
  if (p >= P) return;
  int v = tids[p];
  int prev = (p == 0) ? -1 : tids[p - 1];
  for (int e = prev + 1; e <= v; ++e) ptr[e] = p;
  if (p == P - 1) {
    for (int e = v + 1; e <= E; ++e) ptr[e] = P;
  }
}

__global__ void conv_w1(const float* __restrict__ W1, ushort* __restrict__ W1b, int n) {
  int base = (blockIdx.x * 256 + threadIdx.x) * 4;
  if (base >= n) return;
  float4 v = *(const float4*)(W1 + base);
  ushort4 o;
  o.x = f2bf(v.x); o.y = f2bf(v.y); o.z = f2bf(v.z); o.w = f2bf(v.w);
  *(ushort4*)(W1b + base) = o;
}

__global__ __launch_bounds__(256, 4) void henn_main(
    const float* __restrict__ x,
    const int* __restrict__ tnodes,
    const int* __restrict__ ptr,
    const ushort* __restrict__ W1b,
    const float* __restrict__ b1,
    const float* __restrict__ W2,
    const float* __restrict__ b2,
    float* __restrict__ out,
    int E)
{
  __shared__ __align__(16) ushort Zb[64 * 256];   // 32 KB bf16 Z tile, XOR-swizzled
  const int tid  = threadIdx.x;
  const int wid  = tid >> 6;
  const int lane = tid & 63;
  const int e0   = blockIdx.x * 64;

  // ---- segment bounds: one coalesced load + shfl broadcast ----
  int bidx = e0 + wid * 16 + lane;
  int bnd = 0;
  if (lane < 17) bnd = ptr[min(bidx, E)];

  // ---- Phase 1: gather + segment-sum, bf16 store to LDS ----
  for (int s = 0; s < 16; ++s) {
    const int lo = __shfl(bnd, s);
    const int hi = __shfl(bnd, s + 1);
    float ax = 0.f, ay = 0.f, az = 0.f, aw = 0.f;
    for (int base = lo; base < hi; base += 64) {
      const int cnt = min(64, hi - base);
      const int nd = (lane < cnt) ? tnodes[base + lane] : 0;
      for (int i = 0; i < cnt; ++i) {
        const int node = __shfl(nd, i);
        const float4 v = ((const float4*)(x + (size_t)node * 256))[lane];
        ax += v.x; ay += v.y; az += v.z; aw += v.w;
      }
    }
    const int row = wid * 16 + s;
    ushort4 o; o.x = f2bf(ax); o.y = f2bf(ay); o.z = f2bf(az); o.w = f2bf(aw);
    const int waddr = row * 512 + lane * 8;
    *(ushort4*)((char*)Zb + (waddr ^ ((row & 7) << 4))) = o;
  }
  __syncthreads();

  // ---- Phase 2: Y = Z @ W1^T via MFMA. wave owns h in [64*wid, 64*wid+64) ----
  const int l15 = lane & 15, l4 = lane >> 4;
  const int n0 = wid * 64;
  f32x4 acc[4][4];
#pragma unroll
  for (int mt = 0; mt < 4; ++mt)
#pragma unroll
    for (int nt = 0; nt < 4; ++nt)
      acc[mt][nt] = (f32x4){0.f, 0.f, 0.f, 0.f};

#pragma unroll
  for (int kk = 0; kk < 8; ++kk) {
    bf16x8 a[4];
#pragma unroll
    for (int mt = 0; mt < 4; ++mt) {
      const int row = mt * 16 + l15;
      const int raddr = row * 512 + kk * 64 + l4 * 16;
      a[mt] = *(const bf16x8*)((const char*)Zb + (raddr ^ ((row & 7) << 4)));
    }
#pragma unroll
    for (int nt = 0; nt < 4; ++nt) {
      const int h = n0 + nt * 16 + l15;
      const bf16x8 b = *(const bf16x8*)(W1b + (size_t)h * 256 + kk * 32 + l4 * 8);
#pragma unroll
      for (int mt = 0; mt < 4; ++mt)
        acc[mt][nt] = __builtin_amdgcn_mfma_f32_16x16x32_bf16(a[mt], b, acc[mt][nt], 0, 0, 0);
    }
  }
  __syncthreads();   // all Zb reads done; reuse as reduction scratch

  // ---- Phase 3: second layer + sigmoid ----
  float b1h[4], w2v[4];
#pragma unroll
  for (int nt = 0; nt < 4; ++nt) {
    const int h = n0 + nt * 16 + l15;
    b1h[nt] = b1[h];
    w2v[nt] = W2[h];
  }
  float* red = (float*)Zb;          // [4][64]
#pragma unroll
  for (int mt = 0; mt < 4; ++mt) {
#pragma unroll
    for (int r = 0; r < 4; ++r) {
      float p = 0.f;
#pragma unroll
      for (int nt = 0; nt < 4; ++nt) {
        const float y = acc[mt][nt][r] + b1h[nt];
        p = fmaf(w2v[nt], fmaxf(y, 0.f), p);
      }
      p += __shfl_xor(p, 1);
      p += __shfl_xor(p, 2);
      p += __shfl_xor(p, 4);
      p += __shfl_xor(p, 8);
      if (l15 == 0) red[wid * 64 + mt * 16 + l4 * 4 + r] = p;
    }
  }
  __syncthreads();

  if (tid < 64) {
    const int e = e0 + tid;
    if (e < E) {
      const float v = red[tid] + red[64 + tid] + red[128 + tid] + red[192 + tid] + b2[0];
      out[e] = 1.f / (1.f + expf(-v));
    }
  }
}

extern "C" void kernel_launch(void* const* d_in, const int* in_sizes, int n_in,
                              void* d_out, int out_size, void* d_ws, size_t ws_size,
                              hipStream_t stream) {
  const float* x      = (const float*)d_in[0];
  const int*   tnodes = (const int*)d_in[1];
  const int*   tids   = (const int*)d_in[2];
  const float* W1     = (const float*)d_in[3];
  const float* b1     = (const float*)d_in[4];
  const float* W2     = (const float*)d_in[5];
  const float* b2     = (const float*)d_in[6];
  (void)n_in; (void)ws_size;

  const int P = in_sizes[1];     // 800000
  const int E = out_size;        // 100000

  int*    seg_ptr = (int*)d_ws;
  ushort* W1b     = (ushort*)((char*)d_ws + W1B_OFF);

  build_segptr<<<(P + 255) / 256, 256, 0, stream>>>(tids, seg_ptr, P, E);
  conv_w1<<<(256 * 256 / 4 + 255) / 256, 256, 0, stream>>>(W1, W1b, 256 * 256);

  const int blocks = (E + 63) / 64;
  henn_main<<<blocks, 256, 0, stream>>>(x, tnodes, seg_ptr, W1b, b1, W2, b2,
                                        (float*)d_out, E);
}

// Round 4
// 154.006 us; speedup vs baseline: 6.2281x; 1.1611x over previous
//
#include <hip/hip_runtime.h>
#include <math.h>

// Fused HENN MLP: gather -> segment_sum -> Linear(256,256)+ReLU -> Linear(256,1) -> sigmoid
//
// Pipeline (3 kernels):
//  1. build_segptr: seg_ptr[e] = lower_bound(tids, e) for e in [0,E]  (d_ws)
//  2. conv_w1:      W1 f32 -> bf16 row-major [256][256]               (d_ws)
//  3. henn_main:    1 block = 64 segments, 256 threads (4 waves):
//     Phase 1 (gather, latency-optimized): wave = 4 groups x 16 lanes; group g
//       processes pairs lo+4r+g of the current segment, reading the 1KB row as
//       4 independent float4 chunk loads -> ~16 loads in flight per wave.
//       NOTE: the node-index __shfl MUST run under uniform exec (ds_bpermute
//       reads from inactive source lanes are undefined) — R3 bug. Shuffle is
//       hoisted out of the `idx < cnt` guard.
//       Cross-group reduce via shfl_xor(16/32); bf16 store to XOR-swizzled LDS.
//     Phase 2: Y = relu(Z @ W1^T + b1) via mfma_f32_16x16x32_bf16 (4x4 frags, K=256)
//     Phase 3: y2 = Y @ W2^T + b2 -> sigmoid; shfl + LDS cross-wave reduce.

typedef __attribute__((ext_vector_type(8))) short bf16x8;
typedef __attribute__((ext_vector_type(4))) float f32x4;

#define W1B_OFF (512 * 1024)   // d_ws byte offset of bf16 W1 (seg_ptr needs 400 KB)

__device__ __forceinline__ ushort f2bf(float f) {   // RNE f32->bf16
  unsigned u = __float_as_uint(f);
  unsigned r = (u + 0x7FFF + ((u >> 16) & 1)) >> 16;
  return (ushort)r;
}

__global__ void build_segptr(const int* __restrict__ tids, int* __restrict__ ptr,
                             int P, int E) {
  int p = blockIdx.x * 256 + threadIdx.x;
  if (p >= P) return;
  int v = tids[p];
  int prev = (p == 0) ? -1 : tids[p - 1];
  for (int e = prev + 1; e <= v; ++e) ptr[e] = p;
  if (p == P - 1) {
    for (int e = v + 1; e <= E; ++e) ptr[e] = P;
  }
}

__global__ void conv_w1(const float* __restrict__ W1, ushort* __restrict__ W1b, int n) {
  int base = (blockIdx.x * 256 + threadIdx.x) * 4;
  if (base >= n) return;
  float4 v = *(const float4*)(W1 + base);
  ushort4 o;
  o.x = f2bf(v.x); o.y = f2bf(v.y); o.z = f2bf(v.z); o.w = f2bf(v.w);
  *(ushort4*)(W1b + base) = o;
}

__device__ __forceinline__ void red2(float4& v) {   // reduce across lane groups (+-16, +-32)
  v.x += __shfl_xor(v.x, 16); v.y += __shfl_xor(v.y, 16);
  v.z += __shfl_xor(v.z, 16); v.w += __shfl_xor(v.w, 16);
  v.x += __shfl_xor(v.x, 32); v.y += __shfl_xor(v.y, 32);
  v.z += __shfl_xor(v.z, 32); v.w += __shfl_xor(v.w, 32);
}

__global__ __launch_bounds__(256, 4) void henn_main(
    const float* __restrict__ x,
    const int* __restrict__ tnodes,
    const int* __restrict__ ptr,
    const ushort* __restrict__ W1b,
    const float* __restrict__ b1,
    const float* __restrict__ W2,
    const float* __restrict__ b2,
    float* __restrict__ out,
    int E)
{
  __shared__ __align__(16) ushort Zb[64 * 256];   // 32 KB bf16 Z tile, XOR-swizzled
  const int tid  = threadIdx.x;
  const int wid  = tid >> 6;
  const int lane = tid & 63;
  const int l15  = lane & 15;
  const int l4   = lane >> 4;     // group id 0..3
  const int e0   = blockIdx.x * 64;

  // ---- segment bounds: one coalesced load + shfl broadcast ----
  int bidx = e0 + wid * 16 + lane;
  int bnd = 0;
  if (lane < 17) bnd = ptr[min(bidx, E)];

  // ---- Phase 1: pair-parallel gather + segment-sum ----
  for (int s = 0; s < 16; ++s) {
    const int lo = __shfl(bnd, s);
    const int hi = __shfl(bnd, s + 1);
    float4 a0 = {0,0,0,0}, a1 = {0,0,0,0}, a2 = {0,0,0,0}, a3 = {0,0,0,0};
    for (int base = lo; base < hi; base += 64) {
      const int cnt = min(64, hi - base);      // wave-uniform, >= 1
      const int nd = (lane < cnt) ? tnodes[base + lane] : 0;
      const int rounds = (cnt + 3) >> 2;
      for (int r = 0; r < rounds; ++r) {
        const int idx = r * 4 + l4;            // group l4 takes pair base+idx
        // UNIFORM-EXEC shuffle (source lane always active); clamp keeps it valid
        const int node = __shfl(nd, min(idx, cnt - 1));
        if (idx < cnt) {
          const float4* rowp = (const float4*)(x + (size_t)node * 256) + l15;
          const float4 v0 = rowp[0];
          const float4 v1 = rowp[16];
          const float4 v2 = rowp[32];
          const float4 v3 = rowp[48];
          a0.x += v0.x; a0.y += v0.y; a0.z += v0.z; a0.w += v0.w;
          a1.x += v1.x; a1.y += v1.y; a1.z += v1.z; a1.w += v1.w;
          a2.x += v2.x; a2.y += v2.y; a2.z += v2.z; a2.w += v2.w;
          a3.x += v3.x; a3.y += v3.y; a3.z += v3.z; a3.w += v3.w;
        }
      }
    }
    // cross-group reduction: groups held different pairs of the SAME segment
    red2(a0); red2(a1); red2(a2); red2(a3);
    // lane stores chunk l4 (cols l4*64 + l15*4 ..+3) as bf16 (static select, no indexed array)
    float4 m = (l4 == 0) ? a0 : (l4 == 1) ? a1 : (l4 == 2) ? a2 : a3;
    const int row = wid * 16 + s;
    ushort4 o; o.x = f2bf(m.x); o.y = f2bf(m.y); o.z = f2bf(m.z); o.w = f2bf(m.w);
    const int waddr = row * 512 + lane * 8;
    *(ushort4*)((char*)Zb + (waddr ^ ((row & 7) << 4))) = o;
  }
  __syncthreads();

  // ---- Phase 2: Y = Z @ W1^T via MFMA. wave owns h in [64*wid, 64*wid+64) ----
  const int n0 = wid * 64;
  f32x4 acc[4][4];
#pragma unroll
  for (int mt = 0; mt < 4; ++mt)
#pragma unroll
    for (int nt = 0; nt < 4; ++nt)
      acc[mt][nt] = (f32x4){0.f, 0.f, 0.f, 0.f};

#pragma unroll
  for (int kk = 0; kk < 8; ++kk) {
    bf16x8 a[4];
#pragma unroll
    for (int mt = 0; mt < 4; ++mt) {
      const int row = mt * 16 + l15;
      const int raddr = row * 512 + kk * 64 + l4 * 16;
      a[mt] = *(const bf16x8*)((const char*)Zb + (raddr ^ ((row & 7) << 4)));
    }
#pragma unroll
    for (int nt = 0; nt < 4; ++nt) {
      const int h = n0 + nt * 16 + l15;
      const bf16x8 b = *(const bf16x8*)(W1b + (size_t)h * 256 + kk * 32 + l4 * 8);
#pragma unroll
      for (int mt = 0; mt < 4; ++mt)
        acc[mt][nt] = __builtin_amdgcn_mfma_f32_16x16x32_bf16(a[mt], b, acc[mt][nt], 0, 0, 0);
    }
  }
  __syncthreads();   // all Zb reads done; reuse as reduction scratch

  // ---- Phase 3: second layer + sigmoid ----
  float b1h[4], w2v[4];
#pragma unroll
  for (int nt = 0; nt < 4; ++nt) {
    const int h = n0 + nt * 16 + l15;
    b1h[nt] = b1[h];
    w2v[nt] = W2[h];
  }
  float* red = (float*)Zb;          // [4][64]
#pragma unroll
  for (int mt = 0; mt < 4; ++mt) {
#pragma unroll
    for (int r = 0; r < 4; ++r) {
      float p = 0.f;
#pragma unroll
      for (int nt = 0; nt < 4; ++nt) {
        const float y = acc[mt][nt][r] + b1h[nt];
        p = fmaf(w2v[nt], fmaxf(y, 0.f), p);
      }
      p += __shfl_xor(p, 1);
      p += __shfl_xor(p, 2);
      p += __shfl_xor(p, 4);
      p += __shfl_xor(p, 8);
      if (l15 == 0) red[wid * 64 + mt * 16 + l4 * 4 + r] = p;
    }
  }
  __syncthreads();

  if (tid < 64) {
    const int e = e0 + tid;
    if (e < E) {
      const float v = red[tid] + red[64 + tid] + red[128 + tid] + red[192 + tid] + b2[0];
      out[e] = 1.f / (1.f + expf(-v));
    }
  }
}

extern "C" void kernel_launch(void* const* d_in, const int* in_sizes, int n_in,
                              void* d_out, int out_size, void* d_ws, size_t ws_size,
                              hipStream_t stream) {
  const float* x      = (const float*)d_in[0];
  const int*   tnodes = (const int*)d_in[1];
  const int*   tids   = (const int*)d_in[2];
  const float* W1     = (const float*)d_in[3];
  const float* b1     = (const float*)d_in[4];
  const float* W2     = (const float*)d_in[5];
  const float* b2     = (const float*)d_in[6];
  (void)n_in; (void)ws_size;

  const int P = in_sizes[1];     // 800000
  const int E = out_size;        // 100000

  int*    seg_ptr = (int*)d_ws;
  ushort* W1b     = (ushort*)((char*)d_ws + W1B_OFF);

  build_segptr<<<(P + 255) / 256, 256, 0, stream>>>(tids, seg_ptr, P, E);
  conv_w1<<<(256 * 256 / 4 + 255) / 256, 256, 0, stream>>>(W1, W1b, 256 * 256);

  const int blocks = (E + 63) / 64;
  henn_main<<<blocks, 256, 0, stream>>>(x, tnodes, seg_ptr, W1b, b1, W2, b2,
                                        (float*)d_out, E);
}

// Round 5
// 138.909 us; speedup vs baseline: 6.9050x; 1.1087x over previous
//
#include <hip/hip_runtime.h>
#include <math.h>

// Fused HENN MLP: gather -> segment_sum -> Linear(256,256)+ReLU -> Linear(256,1) -> sigmoid
//
// Split pipeline (R5): the gather is latency/in-flight capped (R4: 5.3 TB/s
// logical delivery, all pipes <36%). Levers: occupancy (LDS-free gather kernel
// at launch_bounds(256,8)) and bytes (x pre-converted to bf16, halving random
// gather traffic).
//
// Kernels (all on `stream`, in order):
//  1. build_segptr: seg_ptr[e] = lower_bound(tids, e)           -> d_ws
//  2. conv_w1:      W1 f32 -> bf16 [256][256]                   -> d_ws
//  3. conv_x:       x  f32 -> bf16 [N][256] (streamed)          -> d_ws
//  4. henn_gather:  segment-sum of bf16 rows, NO LDS, 8 waves/SIMD;
//                   wave = 4 x 16-lane groups, 2 pairs/group/round
//                   (4 loads/lane in flight); f32 accumulate; xor16/32
//                   cross-group reduce; writes Z [E][256] bf16   -> d_ws
//  5. henn_mlp:     stage contiguous Z tile -> swizzled LDS; MFMA
//                   Y=relu(Z@W1^T+b1); y2=Y@W2^T+b2 -> sigmoid -> out
//
// Falls back to the R4 fused kernel if ws_size is too small for x_bf16 + Z.

typedef __attribute__((ext_vector_type(8))) short bf16x8;
typedef __attribute__((ext_vector_type(4))) float f32x4;

__device__ __forceinline__ ushort f2bf(float f) {   // RNE f32->bf16
  unsigned u = __float_as_uint(f);
  unsigned r = (u + 0x7FFF + ((u >> 16) & 1)) >> 16;
  return (ushort)r;
}
__device__ __forceinline__ unsigned pack2(float lo, float hi) {
  return (unsigned)f2bf(lo) | ((unsigned)f2bf(hi) << 16);
}

__global__ void build_segptr(const int* __restrict__ tids, int* __restrict__ ptr,
                             int P, int E) {
  int p = blockIdx.x * 256 + threadIdx.x;
  if (p >= P) return;
  int v = tids[p];
  int prev = (p == 0) ? -1 : tids[p - 1];
  for (int e = prev + 1; e <= v; ++e) ptr[e] = p;
  if (p == P - 1) {
    for (int e = v + 1; e <= E; ++e) ptr[e] = P;
  }
}

__global__ void conv_w1(const float* __restrict__ W1, ushort* __restrict__ W1b, int n) {
  int base = (blockIdx.x * 256 + threadIdx.x) * 4;
  if (base >= n) return;
  float4 v = *(const float4*)(W1 + base);
  ushort4 o;
  o.x = f2bf(v.x); o.y = f2bf(v.y); o.z = f2bf(v.z); o.w = f2bf(v.w);
  *(ushort4*)(W1b + base) = o;
}

__global__ void conv_x(const float* __restrict__ x, ushort* __restrict__ xb, long n) {
  long i = ((long)blockIdx.x * 256 + threadIdx.x) * 8;
  const long stride = (long)gridDim.x * 256 * 8;
  for (; i < n; i += stride) {
    float4 v0 = *(const float4*)(x + i);
    float4 v1 = *(const float4*)(x + i + 4);
    uint4 o;
    o.x = pack2(v0.x, v0.y); o.y = pack2(v0.z, v0.w);
    o.z = pack2(v1.x, v1.y); o.w = pack2(v1.z, v1.w);
    *(uint4*)(xb + i) = o;
  }
}

#define ACC8(c, o)                                                        \
  acc[(o)+0] += __uint_as_float((c).x << 16);                             \
  acc[(o)+1] += __uint_as_float((c).x & 0xffff0000u);                     \
  acc[(o)+2] += __uint_as_float((c).y << 16);                             \
  acc[(o)+3] += __uint_as_float((c).y & 0xffff0000u);                     \
  acc[(o)+4] += __uint_as_float((c).z << 16);                             \
  acc[(o)+5] += __uint_as_float((c).z & 0xffff0000u);                     \
  acc[(o)+6] += __uint_as_float((c).w << 16);                             \
  acc[(o)+7] += __uint_as_float((c).w & 0xffff0000u);

__global__ __launch_bounds__(256, 8) void henn_gather(
    const ushort* __restrict__ xb,
    const int* __restrict__ tnodes,
    const int* __restrict__ ptr,
    ushort* __restrict__ Zg,
    int E)
{
  const int lane = threadIdx.x & 63;
  const int wid  = threadIdx.x >> 6;
  const int l15  = lane & 15;
  const int l4   = lane >> 4;            // group 0..3
  const int e0   = blockIdx.x * 64 + wid * 16;   // wave's 16 segments
  if (e0 >= E) return;
  const int nseg = min(16, E - e0);

  int bnd = 0;
  if (lane < 17) bnd = ptr[min(e0 + lane, E)];

  for (int s = 0; s < nseg; ++s) {
    const int lo = __shfl(bnd, s);
    const int hi = __shfl(bnd, s + 1);
    float acc[16];
#pragma unroll
    for (int j = 0; j < 16; ++j) acc[j] = 0.f;

    for (int base = lo; base < hi; base += 64) {
      const int cnt = min(64, hi - base);              // wave-uniform, >= 1
      const int nd = (lane < cnt) ? tnodes[base + lane] : 0;
      const int rounds = (cnt + 7) >> 3;
      for (int r = 0; r < rounds; ++r) {
        const int iA = r * 8 + l4 * 2;                 // group l4: pairs iA, iA+1
        // uniform-exec shuffles (R3 lesson: never shuffle from inactive lanes)
        const int nodeA = __shfl(nd, min(iA, cnt - 1));
        const int nodeB = __shfl(nd, min(iA + 1, cnt - 1));
        if (iA < cnt) {
          const uint4* rp = (const uint4*)(xb + (size_t)nodeA * 256);
          const uint4 c0 = rp[l15];        // ushorts [l15*8, +8)
          const uint4 c1 = rp[16 + l15];   // ushorts [128+l15*8, +8)
          ACC8(c0, 0) ACC8(c1, 8)
        }
        if (iA + 1 < cnt) {
          const uint4* rp = (const uint4*)(xb + (size_t)nodeB * 256);
          const uint4 c0 = rp[l15];
          const uint4 c1 = rp[16 + l15];
          ACC8(c0, 0) ACC8(c1, 8)
        }
      }
    }
#pragma unroll
    for (int j = 0; j < 16; ++j) {
      acc[j] += __shfl_xor(acc[j], 16);
      acc[j] += __shfl_xor(acc[j], 32);
    }
    if (l4 == 0) {
      uint4 o0, o1;
      o0.x = pack2(acc[0], acc[1]);   o0.y = pack2(acc[2], acc[3]);
      o0.z = pack2(acc[4], acc[5]);   o0.w = pack2(acc[6], acc[7]);
      o1.x = pack2(acc[8], acc[9]);   o1.y = pack2(acc[10], acc[11]);
      o1.z = pack2(acc[12], acc[13]); o1.w = pack2(acc[14], acc[15]);
      uint4* zp = (uint4*)(Zg + (size_t)(e0 + s) * 256);
      zp[l15]      = o0;
      zp[16 + l15] = o1;
    }
  }
}

__global__ __launch_bounds__(256, 4) void henn_mlp(
    const ushort* __restrict__ Zg,
    const ushort* __restrict__ W1b,
    const float* __restrict__ b1,
    const float* __restrict__ W2,
    const float* __restrict__ b2,
    float* __restrict__ out,
    int E)
{
  __shared__ __align__(16) ushort Zb[64 * 256];   // 32 KB, XOR-swizzled
  const int tid  = threadIdx.x;
  const int wid  = tid >> 6;
  const int lane = tid & 63;
  const int l15  = lane & 15;
  const int l4   = lane >> 4;
  const int e0   = blockIdx.x * 64;

  const char* src = (const char*)(Zg + (size_t)e0 * 256);
#pragma unroll
  for (int i = 0; i < 8; ++i) {
    const int off = i * 4096 + tid * 16;
    const uint4 v = *(const uint4*)(src + off);
    const int row = off >> 9;
    *(uint4*)((char*)Zb + (off ^ ((row & 7) << 4))) = v;
  }
  __syncthreads();

  const int n0 = wid * 64;
  f32x4 acc[4][4];
#pragma unroll
  for (int mt = 0; mt < 4; ++mt)
#pragma unroll
    for (int nt = 0; nt < 4; ++nt)
      acc[mt][nt] = (f32x4){0.f, 0.f, 0.f, 0.f};

#pragma unroll
  for (int kk = 0; kk < 8; ++kk) {
    bf16x8 a[4];
#pragma unroll
    for (int mt = 0; mt < 4; ++mt) {
      const int row = mt * 16 + l15;
      const int raddr = row * 512 + kk * 64 + l4 * 16;
      a[mt] = *(const bf16x8*)((const char*)Zb + (raddr ^ ((row & 7) << 4)));
    }
#pragma unroll
    for (int nt = 0; nt < 4; ++nt) {
      const int h = n0 + nt * 16 + l15;
      const bf16x8 b = *(const bf16x8*)(W1b + (size_t)h * 256 + kk * 32 + l4 * 8);
#pragma unroll
      for (int mt = 0; mt < 4; ++mt)
        acc[mt][nt] = __builtin_amdgcn_mfma_f32_16x16x32_bf16(a[mt], b, acc[mt][nt], 0, 0, 0);
    }
  }
  __syncthreads();

  float b1h[4], w2v[4];
#pragma unroll
  for (int nt = 0; nt < 4; ++nt) {
    const int h = n0 + nt * 16 + l15;
    b1h[nt] = b1[h];
    w2v[nt] = W2[h];
  }
  float* red = (float*)Zb;          // [4][64]
#pragma unroll
  for (int mt = 0; mt < 4; ++mt) {
#pragma unroll
    for (int r = 0; r < 4; ++r) {
      float p = 0.f;
#pragma unroll
      for (int nt = 0; nt < 4; ++nt) {
        const float y = acc[mt][nt][r] + b1h[nt];
        p = fmaf(w2v[nt], fmaxf(y, 0.f), p);
      }
      p += __shfl_xor(p, 1);
      p += __shfl_xor(p, 2);
      p += __shfl_xor(p, 4);
      p += __shfl_xor(p, 8);
      if (l15 == 0) red[wid * 64 + mt * 16 + l4 * 4 + r] = p;
    }
  }
  __syncthreads();

  if (tid < 64) {
    const int e = e0 + tid;
    if (e < E) {
      const float v = red[tid] + red[64 + tid] + red[128 + tid] + red[192 + tid] + b2[0];
      out[e] = 1.f / (1.f + expf(-v));
    }
  }
}

// ---------------- R4 fused fallback (ws too small for split path) ----------
__global__ __launch_bounds__(256, 4) void henn_main(
    const float* __restrict__ x,
    const int* __restrict__ tnodes,
    const int* __restrict__ ptr,
    const ushort* __restrict__ W1b,
    const float* __restrict__ b1,
    const float* __restrict__ W2,
    const float* __restrict__ b2,
    float* __restrict__ out,
    int E)
{
  __shared__ __align__(16) ushort Zb[64 * 256];
  const int tid  = threadIdx.x;
  const int wid  = tid >> 6;
  const int lane = tid & 63;
  const int l15  = lane & 15;
  const int l4   = lane >> 4;
  const int e0   = blockIdx.x * 64;

  int bidx = e0 + wid * 16 + lane;
  int bnd = 0;
  if (lane < 17) bnd = ptr[min(bidx, E)];

  for (int s = 0; s < 16; ++s) {
    const int lo = __shfl(bnd, s);
    const int hi = __shfl(bnd, s + 1);
    float4 a0 = {0,0,0,0}, a1 = {0,0,0,0}, a2 = {0,0,0,0}, a3 = {0,0,0,0};
    for (int base = lo; base < hi; base += 64) {
      const int cnt = min(64, hi - base);
      const int nd = (lane < cnt) ? tnodes[base + lane] : 0;
      const int rounds = (cnt + 3) >> 2;
      for (int r = 0; r < rounds; ++r) {
        const int idx = r * 4 + l4;
        const int node = __shfl(nd, min(idx, cnt - 1));
        if (idx < cnt) {
          const float4* rowp = (const float4*)(x + (size_t)node * 256) + l15;
          const float4 v0 = rowp[0];
          const float4 v1 = rowp[16];
          const float4 v2 = rowp[32];
          const float4 v3 = rowp[48];
          a0.x += v0.x; a0.y += v0.y; a0.z += v0.z; a0.w += v0.w;
          a1.x += v1.x; a1.y += v1.y; a1.z += v1.z; a1.w += v1.w;
          a2.x += v2.x; a2.y += v2.y; a2.z += v2.z; a2.w += v2.w;
          a3.x += v3.x; a3.y += v3.y; a3.z += v3.z; a3.w += v3.w;
        }
      }
    }
    a0.x += __shfl_xor(a0.x,16); a0.y += __shfl_xor(a0.y,16); a0.z += __shfl_xor(a0.z,16); a0.w += __shfl_xor(a0.w,16);
    a0.x += __shfl_xor(a0.x,32); a0.y += __shfl_xor(a0.y,32); a0.z += __shfl_xor(a0.z,32); a0.w += __shfl_xor(a0.w,32);
    a1.x += __shfl_xor(a1.x,16); a1.y += __shfl_xor(a1.y,16); a1.z += __shfl_xor(a1.z,16); a1.w += __shfl_xor(a1.w,16);
    a1.x += __shfl_xor(a1.x,32); a1.y += __shfl_xor(a1.y,32); a1.z += __shfl_xor(a1.z,32); a1.w += __shfl_xor(a1.w,32);
    a2.x += __shfl_xor(a2.x,16); a2.y += __shfl_xor(a2.y,16); a2.z += __shfl_xor(a2.z,16); a2.w += __shfl_xor(a2.w,16);
    a2.x += __shfl_xor(a2.x,32); a2.y += __shfl_xor(a2.y,32); a2.z += __shfl_xor(a2.z,32); a2.w += __shfl_xor(a2.w,32);
    a3.x += __shfl_xor(a3.x,16); a3.y += __shfl_xor(a3.y,16); a3.z += __shfl_xor(a3.z,16); a3.w += __shfl_xor(a3.w,16);
    a3.x += __shfl_xor(a3.x,32); a3.y += __shfl_xor(a3.y,32); a3.z += __shfl_xor(a3.z,32); a3.w += __shfl_xor(a3.w,32);
    float4 m = (l4 == 0) ? a0 : (l4 == 1) ? a1 : (l4 == 2) ? a2 : a3;
    const int row = wid * 16 + s;
    ushort4 o; o.x = f2bf(m.x); o.y = f2bf(m.y); o.z = f2bf(m.z); o.w = f2bf(m.w);
    const int waddr = row * 512 + lane * 8;
    *(ushort4*)((char*)Zb + (waddr ^ ((row & 7) << 4))) = o;
  }
  __syncthreads();

  const int n0 = wid * 64;
  f32x4 acc[4][4];
#pragma unroll
  for (int mt = 0; mt < 4; ++mt)
#pragma unroll
    for (int nt = 0; nt < 4; ++nt)
      acc[mt][nt] = (f32x4){0.f, 0.f, 0.f, 0.f};
#pragma unroll
  for (int kk = 0; kk < 8; ++kk) {
    bf16x8 a[4];
#pragma unroll
    for (int mt = 0; mt < 4; ++mt) {
      const int row = mt * 16 + l15;
      const int raddr = row * 512 + kk * 64 + l4 * 16;
      a[mt] = *(const bf16x8*)((const char*)Zb + (raddr ^ ((row & 7) << 4)));
    }
#pragma unroll
    for (int nt = 0; nt < 4; ++nt) {
      const int h = n0 + nt * 16 + l15;
      const bf16x8 b = *(const bf16x8*)(W1b + (size_t)h * 256 + kk * 32 + l4 * 8);
#pragma unroll
      for (int mt = 0; mt < 4; ++mt)
        acc[mt][nt] = __builtin_amdgcn_mfma_f32_16x16x32_bf16(a[mt], b, acc[mt][nt], 0, 0, 0);
    }
  }
  __syncthreads();

  float b1h[4], w2v[4];
#pragma unroll
  for (int nt = 0; nt < 4; ++nt) {
    const int h = n0 + nt * 16 + l15;
    b1h[nt] = b1[h];
    w2v[nt] = W2[h];
  }
  float* red = (float*)Zb;
#pragma unroll
  for (int mt = 0; mt < 4; ++mt) {
#pragma unroll
    for (int r = 0; r < 4; ++r) {
      float p = 0.f;
#pragma unroll
      for (int nt = 0; nt < 4; ++nt) {
        const float y = acc[mt][nt][r] + b1h[nt];
        p = fmaf(w2v[nt], fmaxf(y, 0.f), p);
      }
      p += __shfl_xor(p, 1);
      p += __shfl_xor(p, 2);
      p += __shfl_xor(p, 4);
      p += __shfl_xor(p, 8);
      if (l15 == 0) red[wid * 64 + mt * 16 + l4 * 4 + r] = p;
    }
  }
  __syncthreads();

  if (tid < 64) {
    const int e = e0 + tid;
    if (e < E) {
      const float v = red[tid] + red[64 + tid] + red[128 + tid] + red[192 + tid] + b2[0];
      out[e] = 1.f / (1.f + expf(-v));
    }
  }
}

extern "C" void kernel_launch(void* const* d_in, const int* in_sizes, int n_in,
                              void* d_out, int out_size, void* d_ws, size_t ws_size,
                              hipStream_t stream) {
  const float* x      = (const float*)d_in[0];
  const int*   tnodes = (const int*)d_in[1];
  const int*   tids   = (const int*)d_in[2];
  const float* W1     = (const float*)d_in[3];
  const float* b1     = (const float*)d_in[4];
  const float* W2     = (const float*)d_in[5];
  const float* b2     = (const float*)d_in[6];
  (void)n_in;

  const int P       = in_sizes[1];        // 800000
  const int E       = out_size;           // 100000
  const int n_nodes = in_sizes[0] / 256;  // 100000

  const size_t OFF_W1B  = 512 * 1024;
  const size_t OFF_XB   = 1024 * 1024;
  const size_t xb_bytes = (size_t)n_nodes * 512;
  const size_t off_zg   = OFF_XB + ((xb_bytes + 65535) & ~(size_t)65535);
  const size_t zg_bytes = (size_t)E * 512 + 65536;   // +pad for OOB tile rows
  const size_t need     = off_zg + zg_bytes;

  int*    seg_ptr = (int*)d_ws;
  ushort* W1b     = (ushort*)((char*)d_ws + OFF_W1B);

  build_segptr<<<(P + 255) / 256, 256, 0, stream>>>(tids, seg_ptr, P, E);
  conv_w1<<<(256 * 256 / 4 + 255) / 256, 256, 0, stream>>>(W1, W1b, 256 * 256);

  const int blocks = (E + 63) / 64;

  if (ws_size >= need) {
    ushort* xb = (ushort*)((char*)d_ws + OFF_XB);
    ushort* Zg = (ushort*)((char*)d_ws + off_zg);
    conv_x<<<2048, 256, 0, stream>>>(x, xb, (long)n_nodes * 256);
    henn_gather<<<blocks, 256, 0, stream>>>(xb, tnodes, seg_ptr, Zg, E);
    henn_mlp<<<blocks, 256, 0, stream>>>(Zg, W1b, b1, W2, b2, (float*)d_out, E);
  } else {
    henn_main<<<blocks, 256, 0, stream>>>(x, tnodes, seg_ptr, W1b, b1, W2, b2,
                                          (float*)d_out, E);
  }
}

// Round 6
// 136.337 us; speedup vs baseline: 7.0352x; 1.0189x over previous
//
#include <hip/hip_runtime.h>
#include <math.h>

// Fused HENN MLP: gather -> segment_sum -> Linear(256,256)+ReLU -> Linear(256,1) -> sigmoid
//
// R6 pipeline (3 launches):
//  1. prep (fused):  blocks [0,2048)        : x f32 -> bf16 (nt loads of x)
//                    blocks [2048,2112)     : W1 f32 -> bf16
//                    blocks [2112,2112+3125): seg_ptr[e] = lower_bound(tids,e)
//  2. henn_gather:   sequential-pair segment-sum. 1 wave = 8 segments, whose
//                    pairs are CONTIGUOUS [ptr[e0], ptr[e0+8]). All 64 lanes
//                    process the same pair (uint2 = 8B/lane of the 512B row);
//                    8-deep static row-load pipeline (4KB in flight/wave);
//                    wave-uniform segment-boundary flushes (nt stores of Z).
//                    No LDS, VGPR<64, launch_bounds(256,8) -> 8 waves/SIMD.
//  3. henn_mlp:      stage Z tile (nt loads) -> swizzled LDS; MFMA
//                    Y=relu(Z@W1^T+b1); y2=Y@W2^T+b2 -> sigmoid -> out.
//
// Falls back to the R4 fused kernel if ws_size is too small.

typedef __attribute__((ext_vector_type(8))) short bf16x8;
typedef __attribute__((ext_vector_type(4))) float f32x4;
typedef __attribute__((ext_vector_type(4))) float f4;
typedef __attribute__((ext_vector_type(4))) unsigned u4;
typedef __attribute__((ext_vector_type(2))) unsigned u2;

__device__ __forceinline__ ushort f2bf(float f) {   // RNE f32->bf16
  unsigned u = __float_as_uint(f);
  return (ushort)((u + 0x7FFF + ((u >> 16) & 1)) >> 16);
}
__device__ __forceinline__ unsigned pack2(float lo, float hi) {
  return (unsigned)f2bf(lo) | ((unsigned)f2bf(hi) << 16);
}

#define PREP_CONVX_BLOCKS 2048
#define PREP_W1_BLOCKS    64

__global__ __launch_bounds__(256) void prep(
    const float* __restrict__ x, ushort* __restrict__ xb, long nx,
    const float* __restrict__ W1, ushort* __restrict__ W1b,
    const int* __restrict__ tids, int* __restrict__ ptr, int P, int E,
    int do_convx)
{
  const int b = blockIdx.x;
  if (b < PREP_CONVX_BLOCKS) {
    if (!do_convx) return;
    long i = ((long)b * 256 + threadIdx.x) * 8;
    const long stride = (long)PREP_CONVX_BLOCKS * 256 * 8;
    for (; i < nx; i += stride) {
      const f4 v0 = __builtin_nontemporal_load((const f4*)(x + i));
      const f4 v1 = __builtin_nontemporal_load((const f4*)(x + i + 4));
      u4 o;
      o.x = pack2(v0.x, v0.y); o.y = pack2(v0.z, v0.w);
      o.z = pack2(v1.x, v1.y); o.w = pack2(v1.z, v1.w);
      *(u4*)(xb + i) = o;                      // keep xb cacheable (hot buffer)
    }
  } else if (b < PREP_CONVX_BLOCKS + PREP_W1_BLOCKS) {
    const int base = ((b - PREP_CONVX_BLOCKS) * 256 + threadIdx.x) * 4;
    if (base < 256 * 256) {
      const f4 v = *(const f4*)(W1 + base);
      u2 o; o.x = pack2(v.x, v.y); o.y = pack2(v.z, v.w);
      *(u2*)(W1b + base) = o;
    }
  } else {
    const int p = (b - PREP_CONVX_BLOCKS - PREP_W1_BLOCKS) * 256 + threadIdx.x;
    if (p >= P) return;
    const int v = tids[p];
    const int prev = (p == 0) ? -1 : tids[p - 1];
    for (int e = prev + 1; e <= v; ++e) ptr[e] = p;
    if (p == P - 1) {
      for (int e = v + 1; e <= E; ++e) ptr[e] = P;
    }
  }
}

__global__ __launch_bounds__(256, 8) void henn_gather(
    const ushort* __restrict__ xb,
    const int* __restrict__ tnodes,
    const int* __restrict__ ptr,
    ushort* __restrict__ Zg,
    int E)
{
  const int lane = threadIdx.x & 63;
  const int wid  = threadIdx.x >> 6;
  const int e0   = blockIdx.x * 32 + wid * 8;    // this wave's 8 segments
  if (e0 >= E) return;
  const int nseg = min(8, E - e0);

  int bnd = 0;
  if (lane <= 8) bnd = ptr[min(e0 + lane, E)];   // bounds for segs e0..e0+8
  const int plo = __shfl(bnd, 0);
  const int phi = __shfl(bnd, nseg);

  int s = 0;
  int hi_s = __shfl(bnd, 1);
  float a0 = 0.f, a1 = 0.f, a2 = 0.f, a3 = 0.f;

  const char* xbB = (const char*)xb;
  const int lb = lane * 8;                       // byte offset within row

  for (int base = plo; base < phi; base += 64) {
    const int cnt = min(64, phi - base);         // wave-uniform, >= 1
    const int ndv = tnodes[base + min(lane, cnt - 1)];   // coalesced, clamped
    for (int j = 0; j < cnt; j += 8) {
      const int m = min(8, cnt - j);             // wave-uniform
      // node ids (uniform exec, clamped -> always-valid shuffles/addresses)
      const int n0 = __shfl(ndv, min(j + 0, cnt - 1));
      const int n1 = __shfl(ndv, min(j + 1, cnt - 1));
      const int n2 = __shfl(ndv, min(j + 2, cnt - 1));
      const int n3 = __shfl(ndv, min(j + 3, cnt - 1));
      const int n4 = __shfl(ndv, min(j + 4, cnt - 1));
      const int n5 = __shfl(ndv, min(j + 5, cnt - 1));
      const int n6 = __shfl(ndv, min(j + 6, cnt - 1));
      const int n7 = __shfl(ndv, min(j + 7, cnt - 1));
      // 8 independent row loads in flight (8B/lane, 512B/row/wave)
      const u2 v0 = *(const u2*)(xbB + (size_t)n0 * 512 + lb);
      const u2 v1 = *(const u2*)(xbB + (size_t)n1 * 512 + lb);
      const u2 v2 = *(const u2*)(xbB + (size_t)n2 * 512 + lb);
      const u2 v3 = *(const u2*)(xbB + (size_t)n3 * 512 + lb);
      const u2 v4 = *(const u2*)(xbB + (size_t)n4 * 512 + lb);
      const u2 v5 = *(const u2*)(xbB + (size_t)n5 * 512 + lb);
      const u2 v6 = *(const u2*)(xbB + (size_t)n6 * 512 + lb);
      const u2 v7 = *(const u2*)(xbB + (size_t)n7 * 512 + lb);

#define STEP(K, VK)                                                           \
      if (K < m) {                                                            \
        const int pcur = base + j + K;                                        \
        while (pcur >= hi_s) {        /* wave-uniform segment flush */        \
          u2 oz; oz.x = pack2(a0, a1); oz.y = pack2(a2, a3);                  \
          __builtin_nontemporal_store(oz,                                     \
              (u2*)((char*)Zg + (size_t)(e0 + s) * 512 + lb));                \
          a0 = a1 = a2 = a3 = 0.f;                                            \
          ++s; hi_s = __shfl(bnd, s + 1);                                     \
        }                                                                     \
        a0 += __uint_as_float(VK.x << 16);                                    \
        a1 += __uint_as_float(VK.x & 0xffff0000u);                            \
        a2 += __uint_as_float(VK.y << 16);                                    \
        a3 += __uint_as_float(VK.y & 0xffff0000u);                            \
      }
      STEP(0, v0) STEP(1, v1) STEP(2, v2) STEP(3, v3)
      STEP(4, v4) STEP(5, v5) STEP(6, v6) STEP(7, v7)
#undef STEP
    }
  }
  // flush remaining segments (incl. trailing empties)
  while (s < nseg) {
    u2 oz; oz.x = pack2(a0, a1); oz.y = pack2(a2, a3);
    __builtin_nontemporal_store(oz, (u2*)((char*)Zg + (size_t)(e0 + s) * 512 + lb));
    a0 = a1 = a2 = a3 = 0.f;
    ++s;
  }
}

__global__ __launch_bounds__(256, 4) void henn_mlp(
    const ushort* __restrict__ Zg,
    const ushort* __restrict__ W1b,
    const float* __restrict__ b1,
    const float* __restrict__ W2,
    const float* __restrict__ b2,
    float* __restrict__ out,
    int E)
{
  __shared__ __align__(16) ushort Zb[64 * 256];   // 32 KB, XOR-swizzled
  const int tid  = threadIdx.x;
  const int wid  = tid >> 6;
  const int lane = tid & 63;
  const int l15  = lane & 15;
  const int l4   = lane >> 4;
  const int e0   = blockIdx.x * 64;

  const char* src = (const char*)(Zg + (size_t)e0 * 256);
#pragma unroll
  for (int i = 0; i < 8; ++i) {
    const int off = i * 4096 + tid * 16;
    const u4 v = __builtin_nontemporal_load((const u4*)(src + off));
    const int row = off >> 9;
    *(u4*)((char*)Zb + (off ^ ((row & 7) << 4))) = v;
  }
  __syncthreads();

  const int n0 = wid * 64;
  f32x4 acc[4][4];
#pragma unroll
  for (int mt = 0; mt < 4; ++mt)
#pragma unroll
    for (int nt = 0; nt < 4; ++nt)
      acc[mt][nt] = (f32x4){0.f, 0.f, 0.f, 0.f};

#pragma unroll
  for (int kk = 0; kk < 8; ++kk) {
    bf16x8 a[4];
#pragma unroll
    for (int mt = 0; mt < 4; ++mt) {
      const int row = mt * 16 + l15;
      const int raddr = row * 512 + kk * 64 + l4 * 16;
      a[mt] = *(const bf16x8*)((const char*)Zb + (raddr ^ ((row & 7) << 4)));
    }
#pragma unroll
    for (int nt = 0; nt < 4; ++nt) {
      const int h = n0 + nt * 16 + l15;
      const bf16x8 b = *(const bf16x8*)(W1b + (size_t)h * 256 + kk * 32 + l4 * 8);
#pragma unroll
      for (int mt = 0; mt < 4; ++mt)
        acc[mt][nt] = __builtin_amdgcn_mfma_f32_16x16x32_bf16(a[mt], b, acc[mt][nt], 0, 0, 0);
    }
  }
  __syncthreads();   // all Zb reads done; reuse as reduction scratch

  float b1h[4], w2v[4];
#pragma unroll
  for (int nt = 0; nt < 4; ++nt) {
    const int h = n0 + nt * 16 + l15;
    b1h[nt] = b1[h];
    w2v[nt] = W2[h];
  }
  float* red = (float*)Zb;          // [4][64]
#pragma unroll
  for (int mt = 0; mt < 4; ++mt) {
#pragma unroll
    for (int r = 0; r < 4; ++r) {
      float p = 0.f;
#pragma unroll
      for (int nt = 0; nt < 4; ++nt) {
        const float y = acc[mt][nt][r] + b1h[nt];
        p = fmaf(w2v[nt], fmaxf(y, 0.f), p);
      }
      p += __shfl_xor(p, 1);
      p += __shfl_xor(p, 2);
      p += __shfl_xor(p, 4);
      p += __shfl_xor(p, 8);
      if (l15 == 0) red[wid * 64 + mt * 16 + l4 * 4 + r] = p;
    }
  }
  __syncthreads();

  if (tid < 64) {
    const int e = e0 + tid;
    if (e < E) {
      const float v = red[tid] + red[64 + tid] + red[128 + tid] + red[192 + tid] + b2[0];
      out[e] = 1.f / (1.f + expf(-v));
    }
  }
}

// ---------------- R4 fused fallback (ws too small for split path) ----------
__global__ __launch_bounds__(256, 4) void henn_main(
    const float* __restrict__ x,
    const int* __restrict__ tnodes,
    const int* __restrict__ ptr,
    const ushort* __restrict__ W1b,
    const float* __restrict__ b1,
    const float* __restrict__ W2,
    const float* __restrict__ b2,
    float* __restrict__ out,
    int E)
{
  __shared__ __align__(16) ushort Zb[64 * 256];
  const int tid  = threadIdx.x;
  const int wid  = tid >> 6;
  const int lane = tid & 63;
  const int l15  = lane & 15;
  const int l4   = lane >> 4;
  const int e0   = blockIdx.x * 64;

  int bidx = e0 + wid * 16 + lane;
  int bnd = 0;
  if (lane < 17) bnd = ptr[min(bidx, E)];

  for (int s = 0; s < 16; ++s) {
    const int lo = __shfl(bnd, s);
    const int hi = __shfl(bnd, s + 1);
    float4 a0 = {0,0,0,0}, a1 = {0,0,0,0}, a2 = {0,0,0,0}, a3 = {0,0,0,0};
    for (int base = lo; base < hi; base += 64) {
      const int cnt = min(64, hi - base);
      const int nd = (lane < cnt) ? tnodes[base + lane] : 0;
      const int rounds = (cnt + 3) >> 2;
      for (int r = 0; r < rounds; ++r) {
        const int idx = r * 4 + l4;
        const int node = __shfl(nd, min(idx, cnt - 1));
        if (idx < cnt) {
          const float4* rowp = (const float4*)(x + (size_t)node * 256) + l15;
          const float4 v0 = rowp[0];
          const float4 v1 = rowp[16];
          const float4 v2 = rowp[32];
          const float4 v3 = rowp[48];
          a0.x += v0.x; a0.y += v0.y; a0.z += v0.z; a0.w += v0.w;
          a1.x += v1.x; a1.y += v1.y; a1.z += v1.z; a1.w += v1.w;
          a2.x += v2.x; a2.y += v2.y; a2.z += v2.z; a2.w += v2.w;
          a3.x += v3.x; a3.y += v3.y; a3.z += v3.z; a3.w += v3.w;
        }
      }
    }
    a0.x += __shfl_xor(a0.x,16); a0.y += __shfl_xor(a0.y,16); a0.z += __shfl_xor(a0.z,16); a0.w += __shfl_xor(a0.w,16);
    a0.x += __shfl_xor(a0.x,32); a0.y += __shfl_xor(a0.y,32); a0.z += __shfl_xor(a0.z,32); a0.w += __shfl_xor(a0.w,32);
    a1.x += __shfl_xor(a1.x,16); a1.y += __shfl_xor(a1.y,16); a1.z += __shfl_xor(a1.z,16); a1.w += __shfl_xor(a1.w,16);
    a1.x += __shfl_xor(a1.x,32); a1.y += __shfl_xor(a1.y,32); a1.z += __shfl_xor(a1.z,32); a1.w += __shfl_xor(a1.w,32);
    a2.x += __shfl_xor(a2.x,16); a2.y += __shfl_xor(a2.y,16); a2.z += __shfl_xor(a2.z,16); a2.w += __shfl_xor(a2.w,16);
    a2.x += __shfl_xor(a2.x,32); a2.y += __shfl_xor(a2.y,32); a2.z += __shfl_xor(a2.z,32); a2.w += __shfl_xor(a2.w,32);
    a3.x += __shfl_xor(a3.x,16); a3.y += __shfl_xor(a3.y,16); a3.z += __shfl_xor(a3.z,16); a3.w += __shfl_xor(a3.w,16);
    a3.x += __shfl_xor(a3.x,32); a3.y += __shfl_xor(a3.y,32); a3.z += __shfl_xor(a3.z,32); a3.w += __shfl_xor(a3.w,32);
    float4 m = (l4 == 0) ? a0 : (l4 == 1) ? a1 : (l4 == 2) ? a2 : a3;
    const int row = wid * 16 + s;
    ushort4 o; o.x = f2bf(m.x); o.y = f2bf(m.y); o.z = f2bf(m.z); o.w = f2bf(m.w);
    const int waddr = row * 512 + lane * 8;
    *(ushort4*)((char*)Zb + (waddr ^ ((row & 7) << 4))) = o;
  }
  __syncthreads();

  const int n0 = wid * 64;
  f32x4 acc[4][4];
#pragma unroll
  for (int mt = 0; mt < 4; ++mt)
#pragma unroll
    for (int nt = 0; nt < 4; ++nt)
      acc[mt][nt] = (f32x4){0.f, 0.f, 0.f, 0.f};
#pragma unroll
  for (int kk = 0; kk < 8; ++kk) {
    bf16x8 a[4];
#pragma unroll
    for (int mt = 0; mt < 4; ++mt) {
      const int row = mt * 16 + l15;
      const int raddr = row * 512 + kk * 64 + l4 * 16;
      a[mt] = *(const bf16x8*)((const char*)Zb + (raddr ^ ((row & 7) << 4)));
    }
#pragma unroll
    for (int nt = 0; nt < 4; ++nt) {
      const int h = n0 + nt * 16 + l15;
      const bf16x8 b = *(const bf16x8*)(W1b + (size_t)h * 256 + kk * 32 + l4 * 8);
#pragma unroll
      for (int mt = 0; mt < 4; ++mt)
        acc[mt][nt] = __builtin_amdgcn_mfma_f32_16x16x32_bf16(a[mt], b, acc[mt][nt], 0, 0, 0);
    }
  }
  __syncthreads();

  float b1h[4], w2v[4];
#pragma unroll
  for (int nt = 0; nt < 4; ++nt) {
    const int h = n0 + nt * 16 + l15;
    b1h[nt] = b1[h];
    w2v[nt] = W2[h];
  }
  float* red = (float*)Zb;
#pragma unroll
  for (int mt = 0; mt < 4; ++mt) {
#pragma unroll
    for (int r = 0; r < 4; ++r) {
      float p = 0.f;
#pragma unroll
      for (int nt = 0; nt < 4; ++nt) {
        const float y = acc[mt][nt][r] + b1h[nt];
        p = fmaf(w2v[nt], fmaxf(y, 0.f), p);
      }
      p += __shfl_xor(p, 1);
      p += __shfl_xor(p, 2);
      p += __shfl_xor(p, 4);
      p += __shfl_xor(p, 8);
      if (l15 == 0) red[wid * 64 + mt * 16 + l4 * 4 + r] = p;
    }
  }
  __syncthreads();

  if (tid < 64) {
    const int e = e0 + tid;
    if (e < E) {
      const float v = red[tid] + red[64 + tid] + red[128 + tid] + red[192 + tid] + b2[0];
      out[e] = 1.f / (1.f + expf(-v));
    }
  }
}

extern "C" void kernel_launch(void* const* d_in, const int* in_sizes, int n_in,
                              void* d_out, int out_size, void* d_ws, size_t ws_size,
                              hipStream_t stream) {
  const float* x      = (const float*)d_in[0];
  const int*   tnodes = (const int*)d_in[1];
  const int*   tids   = (const int*)d_in[2];
  const float* W1     = (const float*)d_in[3];
  const float* b1     = (const float*)d_in[4];
  const float* W2     = (const float*)d_in[5];
  const float* b2     = (const float*)d_in[6];
  (void)n_in;

  const int P       = in_sizes[1];        // 800000
  const int E       = out_size;           // 100000
  const int n_nodes = in_sizes[0] / 256;  // 100000

  const size_t OFF_W1B  = 512 * 1024;
  const size_t OFF_XB   = 1024 * 1024;
  const size_t xb_bytes = (size_t)n_nodes * 512;
  const size_t off_zg   = OFF_XB + ((xb_bytes + 65535) & ~(size_t)65535);
  const size_t zg_bytes = (size_t)E * 512 + 65536;
  const size_t need     = off_zg + zg_bytes;

  int*    seg_ptr = (int*)d_ws;
  ushort* W1b     = (ushort*)((char*)d_ws + OFF_W1B);
  ushort* xb      = (ushort*)((char*)d_ws + OFF_XB);
  ushort* Zg      = (ushort*)((char*)d_ws + off_zg);

  const int split_ok   = (ws_size >= need) ? 1 : 0;
  const int prep_grid  = PREP_CONVX_BLOCKS + PREP_W1_BLOCKS + (P + 255) / 256;
  prep<<<prep_grid, 256, 0, stream>>>(x, xb, (long)n_nodes * 256, W1, W1b,
                                      tids, seg_ptr, P, E, split_ok);

  if (split_ok) {
    const int gblocks = (E + 31) / 32;
    henn_gather<<<gblocks, 256, 0, stream>>>(xb, tnodes, seg_ptr, Zg, E);
    const int mblocks = (E + 63) / 64;
    henn_mlp<<<mblocks, 256, 0, stream>>>(Zg, W1b, b1, W2, b2, (float*)d_out, E);
  } else {
    const int blocks = (E + 63) / 64;
    henn_main<<<blocks, 256, 0, stream>>>(x, tnodes, seg_ptr, W1b, b1, W2, b2,
                                          (float*)d_out, E);
  }
}

// Round 7
// 134.819 us; speedup vs baseline: 7.1145x; 1.0113x over previous
//
#include <hip/hip_runtime.h>
#include <math.h>

// Fused HENN MLP: gather -> segment_sum -> Linear(256,256)+ReLU -> Linear(256,1) -> sigmoid
//
// R7 pipeline (3 launches):
//  1. prep (fused):  x->bf16 (nt loads), W1->bf16, seg_ptr build
//  2. henn_gather:   sequential-pair segment-sum, SCALARIZED pair stream:
//                    pair indices are wave-uniform SGPRs -> tnodes[p] is an
//                    s_load (no ds_bpermute chain); two 8-deep load banks
//                    double-buffered -> 16 u2 loads (8KB/wave) in flight;
//                    128-thread blocks, 8 segs/wave, launch_bounds(128,8).
//  3. henn_mlp:      stage Z tile -> swizzled LDS; MFMA Y=relu(Z@W1^T+b1);
//                    y2=Y@W2^T+b2 -> sigmoid -> out.
//
// Falls back to the R4 fused kernel if ws_size is too small.

typedef __attribute__((ext_vector_type(8))) short bf16x8;
typedef __attribute__((ext_vector_type(4))) float f32x4;
typedef __attribute__((ext_vector_type(4))) float f4;
typedef __attribute__((ext_vector_type(4))) unsigned u4;
typedef __attribute__((ext_vector_type(2))) unsigned u2;

__device__ __forceinline__ ushort f2bf(float f) {   // RNE f32->bf16
  unsigned u = __float_as_uint(f);
  return (ushort)((u + 0x7FFF + ((u >> 16) & 1)) >> 16);
}
__device__ __forceinline__ unsigned pack2(float lo, float hi) {
  return (unsigned)f2bf(lo) | ((unsigned)f2bf(hi) << 16);
}

#define PREP_CONVX_BLOCKS 2048
#define PREP_W1_BLOCKS    64

__global__ __launch_bounds__(256) void prep(
    const float* __restrict__ x, ushort* __restrict__ xb, long nx,
    const float* __restrict__ W1, ushort* __restrict__ W1b,
    const int* __restrict__ tids, int* __restrict__ ptr, int P, int E,
    int do_convx)
{
  const int b = blockIdx.x;
  if (b < PREP_CONVX_BLOCKS) {
    if (!do_convx) return;
    long i = ((long)b * 256 + threadIdx.x) * 8;
    const long stride = (long)PREP_CONVX_BLOCKS * 256 * 8;
    for (; i < nx; i += stride) {
      const f4 v0 = __builtin_nontemporal_load((const f4*)(x + i));
      const f4 v1 = __builtin_nontemporal_load((const f4*)(x + i + 4));
      u4 o;
      o.x = pack2(v0.x, v0.y); o.y = pack2(v0.z, v0.w);
      o.z = pack2(v1.x, v1.y); o.w = pack2(v1.z, v1.w);
      *(u4*)(xb + i) = o;                      // keep xb cacheable (hot buffer)
    }
  } else if (b < PREP_CONVX_BLOCKS + PREP_W1_BLOCKS) {
    const int base = ((b - PREP_CONVX_BLOCKS) * 256 + threadIdx.x) * 4;
    if (base < 256 * 256) {
      const f4 v = *(const f4*)(W1 + base);
      u2 o; o.x = pack2(v.x, v.y); o.y = pack2(v.z, v.w);
      *(u2*)(W1b + base) = o;
    }
  } else {
    const int p = (b - PREP_CONVX_BLOCKS - PREP_W1_BLOCKS) * 256 + threadIdx.x;
    if (p >= P) return;
    const int v = tids[p];
    const int prev = (p == 0) ? -1 : tids[p - 1];
    for (int e = prev + 1; e <= v; ++e) ptr[e] = p;
    if (p == P - 1) {
      for (int e = v + 1; e <= E; ++e) ptr[e] = P;
    }
  }
}

__global__ __launch_bounds__(128, 8) void henn_gather(
    const ushort* __restrict__ xb,
    const int* __restrict__ tnodes,
    const int* __restrict__ ptr,
    ushort* __restrict__ Zg,
    int E)
{
  const int lane = threadIdx.x & 63;
  const int wid  = threadIdx.x >> 6;             // 0..1
  const int e0   = blockIdx.x * 16 + wid * 8;    // this wave's 8 segments
  if (e0 >= E) return;
  const int nseg = min(8, E - e0);

  int bnd = 0;
  if (lane <= 8) bnd = ptr[min(e0 + lane, E)];   // bounds for segs e0..e0+8
  const int plo = __builtin_amdgcn_readfirstlane(__shfl(bnd, 0));
  const int phi = __builtin_amdgcn_readfirstlane(__shfl(bnd, nseg));
  const int total = phi - plo;                   // SGPR

  const char* xbB = (const char*)xb;
  const int lb = lane * 8;                       // byte offset within 512B row
  char* zB = (char*)Zg + (size_t)e0 * 512 + lb;

  float a0 = 0.f, a1 = 0.f, a2 = 0.f, a3 = 0.f;
  int s = 0;
  int hi_s = __builtin_amdgcn_readfirstlane(__shfl(bnd, 1));

#define FLUSHCHK(PCUR)                                                        \
  while ((PCUR) >= hi_s) {            /* wave-uniform segment flush */        \
    u2 oz; oz.x = pack2(a0, a1); oz.y = pack2(a2, a3);                        \
    __builtin_nontemporal_store(oz, (u2*)(zB + (size_t)s * 512));             \
    a0 = a1 = a2 = a3 = 0.f;                                                  \
    ++s; hi_s = __builtin_amdgcn_readfirstlane(__shfl(bnd, min(s + 1, 8)));   \
  }

#define ACCV(V)                                                               \
  a0 += __uint_as_float((V).x << 16);                                         \
  a1 += __uint_as_float((V).x & 0xffff0000u);                                 \
  a2 += __uint_as_float((V).y << 16);                                         \
  a3 += __uint_as_float((V).y & 0xffff0000u);

  if (total > 0) {
    const int tmax = total - 1;
    u2 va[8], vb[8];
    // prologue: fill both banks (pairs [0,8) and [8,16)); indices are SGPRs,
    // tnodes[p] is an s_load; clamped tail loads hit the same row (L1).
#pragma unroll
    for (int k = 0; k < 8; ++k) {
      const int p = plo + min(k, tmax);
      va[k] = *(const u2*)(xbB + (size_t)tnodes[p] * 512 + lb);
    }
#pragma unroll
    for (int k = 0; k < 8; ++k) {
      const int p = plo + min(8 + k, tmax);
      vb[k] = *(const u2*)(xbB + (size_t)tnodes[p] * 512 + lb);
    }

    for (int j = 0; j < total; j += 16) {
      // consume bank A (pairs j..j+8)
#pragma unroll
      for (int k = 0; k < 8; ++k) {
        const int pc = j + k;
        if (pc < total) { FLUSHCHK(plo + pc) ACCV(va[k]) }
      }
      // refill bank A for pairs [j+16, j+24)
#pragma unroll
      for (int k = 0; k < 8; ++k) {
        const int p = plo + min(j + 16 + k, tmax);
        va[k] = *(const u2*)(xbB + (size_t)tnodes[p] * 512 + lb);
      }
      // consume bank B (pairs j+8..j+16)
#pragma unroll
      for (int k = 0; k < 8; ++k) {
        const int pc = j + 8 + k;
        if (pc < total) { FLUSHCHK(plo + pc) ACCV(vb[k]) }
      }
      // refill bank B for pairs [j+24, j+32)
#pragma unroll
      for (int k = 0; k < 8; ++k) {
        const int p = plo + min(j + 24 + k, tmax);
        vb[k] = *(const u2*)(xbB + (size_t)tnodes[p] * 512 + lb);
      }
    }
  }
  // flush remaining segments (incl. trailing empties)
  while (s < nseg) {
    u2 oz; oz.x = pack2(a0, a1); oz.y = pack2(a2, a3);
    __builtin_nontemporal_store(oz, (u2*)(zB + (size_t)s * 512));
    a0 = a1 = a2 = a3 = 0.f;
    ++s;
  }
#undef FLUSHCHK
#undef ACCV
}

__global__ __launch_bounds__(256, 4) void henn_mlp(
    const ushort* __restrict__ Zg,
    const ushort* __restrict__ W1b,
    const float* __restrict__ b1,
    const float* __restrict__ W2,
    const float* __restrict__ b2,
    float* __restrict__ out,
    int E)
{
  __shared__ __align__(16) ushort Zb[64 * 256];   // 32 KB, XOR-swizzled
  const int tid  = threadIdx.x;
  const int wid  = tid >> 6;
  const int lane = tid & 63;
  const int l15  = lane & 15;
  const int l4   = lane >> 4;
  const int e0   = blockIdx.x * 64;

  const char* src = (const char*)(Zg + (size_t)e0 * 256);
#pragma unroll
  for (int i = 0; i < 8; ++i) {
    const int off = i * 4096 + tid * 16;
    const u4 v = __builtin_nontemporal_load((const u4*)(src + off));
    const int row = off >> 9;
    *(u4*)((char*)Zb + (off ^ ((row & 7) << 4))) = v;
  }
  __syncthreads();

  const int n0 = wid * 64;
  f32x4 acc[4][4];
#pragma unroll
  for (int mt = 0; mt < 4; ++mt)
#pragma unroll
    for (int nt = 0; nt < 4; ++nt)
      acc[mt][nt] = (f32x4){0.f, 0.f, 0.f, 0.f};

#pragma unroll
  for (int kk = 0; kk < 8; ++kk) {
    bf16x8 a[4];
#pragma unroll
    for (int mt = 0; mt < 4; ++mt) {
      const int row = mt * 16 + l15;
      const int raddr = row * 512 + kk * 64 + l4 * 16;
      a[mt] = *(const bf16x8*)((const char*)Zb + (raddr ^ ((row & 7) << 4)));
    }
#pragma unroll
    for (int nt = 0; nt < 4; ++nt) {
      const int h = n0 + nt * 16 + l15;
      const bf16x8 b = *(const bf16x8*)(W1b + (size_t)h * 256 + kk * 32 + l4 * 8);
#pragma unroll
      for (int mt = 0; mt < 4; ++mt)
        acc[mt][nt] = __builtin_amdgcn_mfma_f32_16x16x32_bf16(a[mt], b, acc[mt][nt], 0, 0, 0);
    }
  }
  __syncthreads();   // all Zb reads done; reuse as reduction scratch

  float b1h[4], w2v[4];
#pragma unroll
  for (int nt = 0; nt < 4; ++nt) {
    const int h = n0 + nt * 16 + l15;
    b1h[nt] = b1[h];
    w2v[nt] = W2[h];
  }
  float* red = (float*)Zb;          // [4][64]
#pragma unroll
  for (int mt = 0; mt < 4; ++mt) {
#pragma unroll
    for (int r = 0; r < 4; ++r) {
      float p = 0.f;
#pragma unroll
      for (int nt = 0; nt < 4; ++nt) {
        const float y = acc[mt][nt][r] + b1h[nt];
        p = fmaf(w2v[nt], fmaxf(y, 0.f), p);
      }
      p += __shfl_xor(p, 1);
      p += __shfl_xor(p, 2);
      p += __shfl_xor(p, 4);
      p += __shfl_xor(p, 8);
      if (l15 == 0) red[wid * 64 + mt * 16 + l4 * 4 + r] = p;
    }
  }
  __syncthreads();

  if (tid < 64) {
    const int e = e0 + tid;
    if (e < E) {
      const float v = red[tid] + red[64 + tid] + red[128 + tid] + red[192 + tid] + b2[0];
      out[e] = 1.f / (1.f + expf(-v));
    }
  }
}

// ---------------- R4 fused fallback (ws too small for split path) ----------
__global__ __launch_bounds__(256, 4) void henn_main(
    const float* __restrict__ x,
    const int* __restrict__ tnodes,
    const int* __restrict__ ptr,
    const ushort* __restrict__ W1b,
    const float* __restrict__ b1,
    const float* __restrict__ W2,
    const float* __restrict__ b2,
    float* __restrict__ out,
    int E)
{
  __shared__ __align__(16) ushort Zb[64 * 256];
  const int tid  = threadIdx.x;
  const int wid  = tid >> 6;
  const int lane = tid & 63;
  const int l15  = lane & 15;
  const int l4   = lane >> 4;
  const int e0   = blockIdx.x * 64;

  int bidx = e0 + wid * 16 + lane;
  int bnd = 0;
  if (lane < 17) bnd = ptr[min(bidx, E)];

  for (int s = 0; s < 16; ++s) {
    const int lo = __shfl(bnd, s);
    const int hi = __shfl(bnd, s + 1);
    float4 a0 = {0,0,0,0}, a1 = {0,0,0,0}, a2 = {0,0,0,0}, a3 = {0,0,0,0};
    for (int base = lo; base < hi; base += 64) {
      const int cnt = min(64, hi - base);
      const int nd = (lane < cnt) ? tnodes[base + lane] : 0;
      const int rounds = (cnt + 3) >> 2;
      for (int r = 0; r < rounds; ++r) {
        const int idx = r * 4 + l4;
        const int node = __shfl(nd, min(idx, cnt - 1));
        if (idx < cnt) {
          const float4* rowp = (const float4*)(x + (size_t)node * 256) + l15;
          const float4 v0 = rowp[0];
          const float4 v1 = rowp[16];
          const float4 v2 = rowp[32];
          const float4 v3 = rowp[48];
          a0.x += v0.x; a0.y += v0.y; a0.z += v0.z; a0.w += v0.w;
          a1.x += v1.x; a1.y += v1.y; a1.z += v1.z; a1.w += v1.w;
          a2.x += v2.x; a2.y += v2.y; a2.z += v2.z; a2.w += v2.w;
          a3.x += v3.x; a3.y += v3.y; a3.z += v3.z; a3.w += v3.w;
        }
      }
    }
    a0.x += __shfl_xor(a0.x,16); a0.y += __shfl_xor(a0.y,16); a0.z += __shfl_xor(a0.z,16); a0.w += __shfl_xor(a0.w,16);
    a0.x += __shfl_xor(a0.x,32); a0.y += __shfl_xor(a0.y,32); a0.z += __shfl_xor(a0.z,32); a0.w += __shfl_xor(a0.w,32);
    a1.x += __shfl_xor(a1.x,16); a1.y += __shfl_xor(a1.y,16); a1.z += __shfl_xor(a1.z,16); a1.w += __shfl_xor(a1.w,16);
    a1.x += __shfl_xor(a1.x,32); a1.y += __shfl_xor(a1.y,32); a1.z += __shfl_xor(a1.z,32); a1.w += __shfl_xor(a1.w,32);
    a2.x += __shfl_xor(a2.x,16); a2.y += __shfl_xor(a2.y,16); a2.z += __shfl_xor(a2.z,16); a2.w += __shfl_xor(a2.w,16);
    a2.x += __shfl_xor(a2.x,32); a2.y += __shfl_xor(a2.y,32); a2.z += __shfl_xor(a2.z,32); a2.w += __shfl_xor(a2.w,32);
    a3.x += __shfl_xor(a3.x,16); a3.y += __shfl_xor(a3.y,16); a3.z += __shfl_xor(a3.z,16); a3.w += __shfl_xor(a3.w,16);
    a3.x += __shfl_xor(a3.x,32); a3.y += __shfl_xor(a3.y,32); a3.z += __shfl_xor(a3.z,32); a3.w += __shfl_xor(a3.w,32);
    float4 m = (l4 == 0) ? a0 : (l4 == 1) ? a1 : (l4 == 2) ? a2 : a3;
    const int row = wid * 16 + s;
    ushort4 o; o.x = f2bf(m.x); o.y = f2bf(m.y); o.z = f2bf(m.z); o.w = f2bf(m.w);
    const int waddr = row * 512 + lane * 8;
    *(ushort4*)((char*)Zb + (waddr ^ ((row & 7) << 4))) = o;
  }
  __syncthreads();

  const int n0 = wid * 64;
  f32x4 acc[4][4];
#pragma unroll
  for (int mt = 0; mt < 4; ++mt)
#pragma unroll
    for (int nt = 0; nt < 4; ++nt)
      acc[mt][nt] = (f32x4){0.f, 0.f, 0.f, 0.f};
#pragma unroll
  for (int kk = 0; kk < 8; ++kk) {
    bf16x8 a[4];
#pragma unroll
    for (int mt = 0; mt < 4; ++mt) {
      const int row = mt * 16 + l15;
      const int raddr = row * 512 + kk * 64 + l4 * 16;
      a[mt] = *(const bf16x8*)((const char*)Zb + (raddr ^ ((row & 7) << 4)));
    }
#pragma unroll
    for (int nt = 0; nt < 4; ++nt) {
      const int h = n0 + nt * 16 + l15;
      const bf16x8 b = *(const bf16x8*)(W1b + (size_t)h * 256 + kk * 32 + l4 * 8);
#pragma unroll
      for (int mt = 0; mt < 4; ++mt)
        acc[mt][nt] = __builtin_amdgcn_mfma_f32_16x16x32_bf16(a[mt], b, acc[mt][nt], 0, 0, 0);
    }
  }
  __syncthreads();

  float b1h[4], w2v[4];
#pragma unroll
  for (int nt = 0; nt < 4; ++nt) {
    const int h = n0 + nt * 16 + l15;
    b1h[nt] = b1[h];
    w2v[nt] = W2[h];
  }
  float* red = (float*)Zb;
#pragma unroll
  for (int mt = 0; mt < 4; ++mt) {
#pragma unroll
    for (int r = 0; r < 4; ++r) {
      float p = 0.f;
#pragma unroll
      for (int nt = 0; nt < 4; ++nt) {
        const float y = acc[mt][nt][r] + b1h[nt];
        p = fmaf(w2v[nt], fmaxf(y, 0.f), p);
      }
      p += __shfl_xor(p, 1);
      p += __shfl_xor(p, 2);
      p += __shfl_xor(p, 4);
      p += __shfl_xor(p, 8);
      if (l15 == 0) red[wid * 64 + mt * 16 + l4 * 4 + r] = p;
    }
  }
  __syncthreads();

  if (tid < 64) {
    const int e = e0 + tid;
    if (e < E) {
      const float v = red[tid] + red[64 + tid] + red[128 + tid] + red[192 + tid] + b2[0];
      out[e] = 1.f / (1.f + expf(-v));
    }
  }
}

extern "C" void kernel_launch(void* const* d_in, const int* in_sizes, int n_in,
                              void* d_out, int out_size, void* d_ws, size_t ws_size,
                              hipStream_t stream) {
  const float* x      = (const float*)d_in[0];
  const int*   tnodes = (const int*)d_in[1];
  const int*   tids   = (const int*)d_in[2];
  const float* W1     = (const float*)d_in[3];
  const float* b1     = (const float*)d_in[4];
  const float* W2     = (const float*)d_in[5];
  const float* b2     = (const float*)d_in[6];
  (void)n_in;

  const int P       = in_sizes[1];        // 800000
  const int E       = out_size;           // 100000
  const int n_nodes = in_sizes[0] / 256;  // 100000

  const size_t OFF_W1B  = 512 * 1024;
  const size_t OFF_XB   = 1024 * 1024;
  const size_t xb_bytes = (size_t)n_nodes * 512;
  const size_t off_zg   = OFF_XB + ((xb_bytes + 65535) & ~(size_t)65535);
  const size_t zg_bytes = (size_t)E * 512 + 65536;
  const size_t need     = off_zg + zg_bytes;

  int*    seg_ptr = (int*)d_ws;
  ushort* W1b     = (ushort*)((char*)d_ws + OFF_W1B);
  ushort* xb      = (ushort*)((char*)d_ws + OFF_XB);
  ushort* Zg      = (ushort*)((char*)d_ws + off_zg);

  const int split_ok   = (ws_size >= need) ? 1 : 0;
  const int prep_grid  = PREP_CONVX_BLOCKS + PREP_W1_BLOCKS + (P + 255) / 256;
  prep<<<prep_grid, 256, 0, stream>>>(x, xb, (long)n_nodes * 256, W1, W1b,
                                      tids, seg_ptr, P, E, split_ok);

  if (split_ok) {
    const int gblocks = (E + 15) / 16;
    henn_gather<<<gblocks, 128, 0, stream>>>(xb, tnodes, seg_ptr, Zg, E);
    const int mblocks = (E + 63) / 64;
    henn_mlp<<<mblocks, 256, 0, stream>>>(Zg, W1b, b1, W2, b2, (float*)d_out, E);
  } else {
    const int blocks = (E + 63) / 64;
    henn_main<<<blocks, 256, 0, stream>>>(x, tnodes, seg_ptr, W1b, b1, W2, b2,
                                          (float*)d_out, E);
  }
}